// Round 9
// baseline (218.671 us; speedup 1.0000x reference)
//
#include <hip/hip_runtime.h>
#include <cstdint>

typedef unsigned short ushort_t;
typedef __attribute__((ext_vector_type(8))) short v8s;
typedef __attribute__((ext_vector_type(4))) short v4s;
typedef __attribute__((ext_vector_type(2))) unsigned v2u;
typedef __attribute__((ext_vector_type(4))) float v4f;

#define MFMA(a, b, c) __builtin_amdgcn_mfma_f32_16x16x32_bf16(a, b, c, 0, 0, 0)
#define QSCALE 0.18033688011112042f   // (1/8) * log2(e): attn softmax runs in exp2 space

__device__ __forceinline__ float bf2f(ushort_t u) {
    union { unsigned u; float f; } x; x.u = ((unsigned)u) << 16; return x.f;
}
__device__ __forceinline__ short f2bf(float f) {
    union { float f; unsigned u; } x; x.f = f;
    unsigned r = x.u + 0x7fffu + ((x.u >> 16) & 1u);   // RNE
    return (short)(r >> 16);
}

// ---------------- dtype detect: flag=1 if x is bf16-packed, 0 if fp32 ----------------
__global__ void detect_dtype(const unsigned* __restrict__ x, int* __restrict__ flag) {
    __shared__ int cnt;
    if (threadIdx.x == 0) cnt = 0;
    __syncthreads();
    unsigned w = x[threadIdx.x];
    int e = (w >> 7) & 0xFF;
    int hit = ((e >= 96 && e <= 135) || (w & 0xFFFFu) == 0) ? 1 : 0;
    atomicAdd(&cnt, hit);
    __syncthreads();
    if (threadIdx.x == 0) *flag = (cnt >= 160) ? 1 : 0;
}

// ---------------- convert x -> internal bf16 (8 elems/thread) ----------------
__global__ __launch_bounds__(256) void cvt_x(const void* __restrict__ xin,
                                             ushort_t* __restrict__ xb,
                                             const int* __restrict__ flagp, int n8) {
    int i = blockIdx.x * 256 + threadIdx.x;
    if (i >= n8) return;
    if (*flagp) {
        ((v8s*)xb)[i] = ((const v8s*)xin)[i];
    } else {
        const float* xf = (const float*)xin + (size_t)i * 8;
        v8s o;
        #pragma unroll
        for (int j = 0; j < 8; ++j) o[j] = f2bf(xf[j]);
        ((v8s*)xb)[i] = o;
    }
}

// ---------------- convert + transpose weights: out[c][r] = bf16(in[r][c]) ----------------
__global__ __launch_bounds__(256) void cvt_transpose(const void* __restrict__ in,
                                                     ushort_t* __restrict__ out,
                                                     const int* __restrict__ flagp,
                                                     int R, int C) {
    __shared__ ushort_t tile[32][33];
    int bx = blockIdx.x * 32, by = blockIdx.y * 32;
    int tx = threadIdx.x, ty = threadIdx.y;
    int isbf = *flagp;
    for (int i = ty; i < 32; i += 8) {
        size_t idx = (size_t)(by + i) * C + bx + tx;
        tile[i][tx] = isbf ? ((const ushort_t*)in)[idx]
                           : (ushort_t)f2bf(((const float*)in)[idx]);
    }
    __syncthreads();
    for (int i = ty; i < 32; i += 8) out[(size_t)(bx + i) * R + by + tx] = tile[tx][i];
}

// ---------------- RoPE table: tab[t][0:32]=cos(bf16-rounded), [32:64]=sin ----------------
__global__ __launch_bounds__(256) void rope_table(float* __restrict__ tab) {
    int idx = blockIdx.x * 256 + threadIdx.x;   // 65536 = 2048*32
    int t = idx >> 5, d = idx & 31;
    float inv_freq = __expf(-(float)d * 0.28782313662425575f);  // 10000^(-d/32)
    float ang = (float)t * inv_freq;
    float sn, cs;
    sincosf(ang, &sn, &cs);
    tab[t * 64 + d]      = bf2f((ushort_t)f2bf(cs));
    tab[t * 64 + 32 + d] = bf2f((ushort_t)f2bf(sn));
}

// ---------------- GEMM: C[M][N] = A[M][K] * BT[N][K]^T, bf16 in ----------------
// MODE 1: C store, fp32 if *flagp==0 else bf16 (out-proj).
// MODE 2: fused RoPE epilogue -> writes Qr (scaled), Kr, Vt (tiled); C unused.
template <int MODE>
__global__ __launch_bounds__(256) void gemm_bt(const ushort_t* __restrict__ A,
                                               const ushort_t* __restrict__ BT,
                                               void* __restrict__ C,
                                               const int* __restrict__ flagp,
                                               int M, int N, int K,
                                               ushort_t* __restrict__ Qp,
                                               ushort_t* __restrict__ Kp,
                                               ushort_t* __restrict__ Vp,
                                               const float* __restrict__ tab) {
    __shared__ __align__(16) ushort_t As[128 * 32];
    __shared__ __align__(16) ushort_t Bs[128 * 32];
    int tid = threadIdx.x;
    int lane = tid & 63;
    int lr = lane & 15, lc = lane >> 4;
    int w = tid >> 6;
    int wr = (w >> 1) * 64, wc = (w & 1) * 64;
    int m0 = blockIdx.y * 128, n0 = blockIdx.x * 128;

    int c0 = tid, c1 = tid + 256;
    int r0 = c0 >> 2, s0 = c0 & 3;
    int r1 = c1 >> 2, s1 = c1 & 3;

    v4f acc[4][4] = {};

    for (int kt = 0; kt < K; kt += 32) {
        v8s a0 = *(const v8s*)(A + (size_t)(m0 + r0) * K + kt + s0 * 8);
        v8s a1 = *(const v8s*)(A + (size_t)(m0 + r1) * K + kt + s1 * 8);
        v8s b0 = *(const v8s*)(BT + (size_t)(n0 + r0) * K + kt + s0 * 8);
        v8s b1 = *(const v8s*)(BT + (size_t)(n0 + r1) * K + kt + s1 * 8);
        __syncthreads();
        *(v8s*)(As + (size_t)c0 * 8) = a0;
        *(v8s*)(As + (size_t)c1 * 8) = a1;
        *(v8s*)(Bs + (size_t)c0 * 8) = b0;
        *(v8s*)(Bs + (size_t)c1 * 8) = b1;
        __syncthreads();

        v8s af[4], bfr[4];
        #pragma unroll
        for (int i = 0; i < 4; ++i)
            af[i] = *(const v8s*)(As + (wr + i * 16 + lr) * 32 + lc * 8);
        #pragma unroll
        for (int j = 0; j < 4; ++j)
            bfr[j] = *(const v8s*)(Bs + (wc + j * 16 + lr) * 32 + lc * 8);
        #pragma unroll
        for (int i = 0; i < 4; ++i)
            #pragma unroll
            for (int j = 0; j < 4; ++j)
                acc[i][j] = MFMA(af[i], bfr[j], acc[i][j]);
    }

    if (MODE == 1) {
        int store_f32 = (*flagp == 0);
        #pragma unroll
        for (int i = 0; i < 4; ++i)
            #pragma unroll
            for (int j = 0; j < 4; ++j)
                #pragma unroll
                for (int r = 0; r < 4; ++r) {
                    int row = m0 + wr + i * 16 + lc * 4 + r;
                    int col = n0 + wc + j * 16 + lr;
                    if (store_f32)
                        ((float*)C)[(size_t)row * N + col] = acc[i][j][r];
                    else
                        ((ushort_t*)C)[(size_t)row * N + col] = (ushort_t)f2bf(acc[i][j][r]);
                }
    } else {  // MODE 2: fused RoPE + reshape epilogue (N=3072 qkv GEMM)
        int region = n0 >> 10;                  // 0=Q 1=K 2=V
        int h = ((n0 & 1023) + wc) >> 6;
        if (region < 2) {
            const float sc = (region == 0) ? QSCALE : 1.0f;
            ushort_t* dst = (region == 0) ? Qp : Kp;
            #pragma unroll
            for (int i = 0; i < 4; ++i)
                #pragma unroll
                for (int j = 0; j < 2; ++j) {   // d = j*16+lr in [0,32); partner acc[i][j+2]
                    int d = j * 16 + lr;
                    #pragma unroll
                    for (int r = 0; r < 4; ++r) {
                        int tg = m0 + wr + i * 16 + lc * 4 + r;
                        int b = tg >> 11, tt = tg & 2047;
                        float cs = tab[tt * 64 + d], sn = tab[tt * 64 + 32 + d];
                        float x1 = acc[i][j][r], x2 = acc[i][j + 2][r];
                        size_t base = ((size_t)(b * 16 + h) * 2048 + tt) * 64 + d;
                        dst[base]      = (ushort_t)f2bf((x1 * cs - x2 * sn) * sc);
                        dst[base + 32] = (ushort_t)f2bf((x2 * cs + x1 * sn) * sc);
                    }
                }
        } else {  // V tiled: Vt[bh][s_tile][d*32 + s_in]
            #pragma unroll
            for (int i = 0; i < 4; ++i)
                #pragma unroll
                for (int j = 0; j < 4; ++j) {
                    int d = j * 16 + lr;
                    int tg0 = m0 + wr + i * 16 + lc * 4;
                    int b = tg0 >> 11, tt = tg0 & 2047;
                    v4s pk;
                    #pragma unroll
                    for (int r = 0; r < 4; ++r) pk[r] = f2bf(acc[i][j][r]);
                    size_t base = (size_t)(b * 16 + h) * 131072 + (size_t)(tt >> 5) * 2048
                                + (size_t)d * 32 + (tt & 31);
                    *(v4s*)(Vp + base) = pk;
                }
        }
    }
}

// ---------------- flash attention: 4 waves/block, 256 q/block, LDS-staged KV ----------------
// Block cooperatively stages each 32-s K/V tile into LDS (double-buffered, 1 barrier/tile);
// all 4 waves (64 q each) share it -> KV global traffic 128 MB total (8x less than R8).
// S^T = K*Q^T (stats lane-local in q). No-max exp2 softmax. K rows XOR-swizzled in LDS.
__global__ __launch_bounds__(256) void attn(const ushort_t* __restrict__ Qr,
                                            const ushort_t* __restrict__ Kr,
                                            const ushort_t* __restrict__ Vt,
                                            ushort_t* __restrict__ AO) {
    __shared__ __align__(16) ushort_t Ks[2][2048];   // [s 32][d 64], chunk^=(row&7) swizzle
    __shared__ __align__(16) ushort_t Vs[2][2048];   // [d 64][s 32], linear
    __shared__ __align__(16) ushort_t P[4][2560];    // per-wave [q 64][s 32 pad 40]
    int tid = threadIdx.x, lane = tid & 63, W = tid >> 6;
    int lr = lane & 15, lc = lane >> 4;
    int L = blockIdx.x;                               // 256 blocks
    int bh = (L & 7) * 4 + ((L >> 3) & 3);            // XCD x owns bh 4x..4x+3 (if %8 maps)
    int qt = L >> 5;                                  // 0..7
    int q0 = qt * 256 + W * 64;
    int b = bh >> 4, h = bh & 15;
    const ushort_t* Qb = Qr + ((size_t)bh * 2048 + q0) * 64;
    const ushort_t* Kb = Kr + (size_t)bh * 131072;
    const ushort_t* Vb = Vt + (size_t)bh * 131072;
    ushort_t* Pw = P[W];

    // staging coords: K row/chunk; V linear chunk
    int krow = tid >> 3, kchk = tid & 7;
    const ushort_t* Kg = Kb + (size_t)krow * 64 + kchk * 8;     // + tile*2048
    int klds = krow * 64 + (kchk ^ (krow & 7)) * 8;
    const ushort_t* Vg = Vb + (size_t)tid * 8;                  // + tile*2048
    int vlds = tid * 8;

    v8s qf[4][2];
    #pragma unroll
    for (int jq = 0; jq < 4; ++jq)
        #pragma unroll
        for (int kk = 0; kk < 2; ++kk)
            qf[jq][kk] = *(const v8s*)(Qb + (size_t)(jq * 16 + lr) * 64 + kk * 32 + lc * 8);

    v4f o[4][4] = {};
    float li[4] = {0.f, 0.f, 0.f, 0.f};

    // preload tile 0 into buf0; issue loads for tile 1
    v8s kreg = *(const v8s*)(Kg);
    v8s vreg = *(const v8s*)(Vg);
    *(v8s*)(&Ks[0][klds]) = kreg;
    *(v8s*)(&Vs[0][vlds]) = vreg;
    kreg = *(const v8s*)(Kg + 2048);
    vreg = *(const v8s*)(Vg + 2048);
    __syncthreads();

    #pragma unroll 1
    for (int t = 0; t < 64; ++t) {
        int p = t & 1;
        const ushort_t* Kl = Ks[p];
        const ushort_t* Vl = Vs[p];

        // fragments from LDS
        v8s kf[2][2], vf[4];
        #pragma unroll
        for (int hh = 0; hh < 2; ++hh)
            #pragma unroll
            for (int kk = 0; kk < 2; ++kk)
                kf[hh][kk] = *(const v8s*)(Kl + (hh * 16 + lr) * 64 + (((kk * 4 + lc) ^ (lr & 7)) * 8));
        #pragma unroll
        for (int i = 0; i < 4; ++i)
            vf[i] = *(const v8s*)(Vl + (i * 16 + lr) * 32 + lc * 8);

        v4f St[2][4] = {};
        #pragma unroll
        for (int hh = 0; hh < 2; ++hh)
            #pragma unroll
            for (int jq = 0; jq < 4; ++jq) {
                St[hh][jq] = MFMA(kf[hh][0], qf[jq][0], St[hh][jq]);
                St[hh][jq] = MFMA(kf[hh][1], qf[jq][1], St[hh][jq]);
            }

        // stage tile t+1 into other buffer (loads were issued last iteration)
        if (t + 1 < 64) {
            *(v8s*)(&Ks[p ^ 1][klds]) = kreg;
            *(v8s*)(&Vs[p ^ 1][vlds]) = vreg;
        }
        if (t + 2 < 64) {
            kreg = *(const v8s*)(Kg + (size_t)(t + 2) * 2048);
            vreg = *(const v8s*)(Vg + (size_t)(t + 2) * 2048);
        }

        // softmax (exp2 space) + pack P
        #pragma unroll
        for (int jq = 0; jq < 4; ++jq)
            #pragma unroll
            for (int hh = 0; hh < 2; ++hh) {
                #pragma unroll
                for (int r = 0; r < 4; ++r) {
                    float ev = __builtin_amdgcn_exp2f(St[hh][jq][r]);
                    St[hh][jq][r] = ev;
                    li[jq] += ev;
                }
                unsigned d0 = __builtin_amdgcn_perm(__float_as_uint(St[hh][jq][1]),
                                                    __float_as_uint(St[hh][jq][0]), 0x07060302u);
                unsigned d1 = __builtin_amdgcn_perm(__float_as_uint(St[hh][jq][3]),
                                                    __float_as_uint(St[hh][jq][2]), 0x07060302u);
                v2u pk = {d0, d1};
                *(v2u*)(Pw + (jq * 16 + lr) * 40 + hh * 16 + lc * 4) = pk;
            }
        __builtin_amdgcn_s_waitcnt(0xc07f);   // lgkmcnt(0): P visible (same wave)
        #pragma unroll
        for (int jq = 0; jq < 4; ++jq) {
            v8s pf = *(const v8s*)(Pw + (jq * 16 + lr) * 40 + lc * 8);
            #pragma unroll
            for (int i = 0; i < 4; ++i)
                o[i][jq] = MFMA(vf[i], pf, o[i][jq]);
        }
        __syncthreads();   // staging of t+1 visible; all waves done reading buf p
    }

    // epilogue: li reduce + normalize + store (each wave owns its 64 q-rows)
    #pragma unroll
    for (int jq = 0; jq < 4; ++jq) {
        li[jq] += __shfl_xor(li[jq], 16);
        li[jq] += __shfl_xor(li[jq], 32);
        float inv = 1.0f / li[jq];
        int t = q0 + jq * 16 + lr;
        #pragma unroll
        for (int i = 0; i < 4; ++i) {
            v4s pk;
            #pragma unroll
            for (int r = 0; r < 4; ++r) pk[r] = f2bf(o[i][jq][r] * inv);
            *(v4s*)(AO + (size_t)(b * 2048 + t) * 1024 + h * 64 + i * 16 + lc * 4) = pk;
        }
    }
}

extern "C" void kernel_launch(void* const* d_in, const int* in_sizes, int n_in,
                              void* d_out, int out_size, void* d_ws, size_t ws_size,
                              hipStream_t stream) {
    char* ws = (char*)d_ws;
    int*      flag  = (int*)ws;                      // 256 B
    ushort_t* wqkvT = (ushort_t*)(ws + 256);         // 6 MB
    ushort_t* woT   = (ushort_t*)(ws + 6291712);     // 2 MB
    ushort_t* xb    = (ushort_t*)(ws + 8388864);     // 8 MB
    ushort_t* Qr    = (ushort_t*)(ws + 16777472);    // 8 MB
    ushort_t* Kr    = (ushort_t*)(ws + 25166080);    // 8 MB
    ushort_t* Vt    = (ushort_t*)(ws + 33554688);    // 8 MB
    ushort_t* AO    = (ushort_t*)(ws + 41943296);    // 8 MB
    float*    tab   = (float*)(ws + 50331904);       // 512 KB

    detect_dtype<<<1, 256, 0, stream>>>((const unsigned*)d_in[0], flag);
    rope_table<<<256, 256, 0, stream>>>(tab);
    cvt_x<<<2048, 256, 0, stream>>>(d_in[0], xb, flag, 524288);
    dim3 tb(32, 8);
    cvt_transpose<<<dim3(96, 32), tb, 0, stream>>>(d_in[1], wqkvT, flag, 1024, 3072);
    cvt_transpose<<<dim3(32, 32), tb, 0, stream>>>(d_in[2], woT, flag, 1024, 1024);
    gemm_bt<2><<<dim3(24, 32), 256, 0, stream>>>(xb, wqkvT, nullptr, flag, 4096, 3072, 1024,
                                                 Qr, Kr, Vt, tab);
    attn<<<256, 256, 0, stream>>>(Qr, Kr, Vt, AO);
    gemm_bt<1><<<dim3(8, 32), 256, 0, stream>>>(AO, woT, d_out, flag, 4096, 1024, 1024,
                                                nullptr, nullptr, nullptr, nullptr);
}

// Round 10
// 211.729 us; speedup vs baseline: 1.0328x; 1.0328x over previous
//
#include <hip/hip_runtime.h>
#include <cstdint>

typedef unsigned short ushort_t;
typedef __attribute__((ext_vector_type(8))) short v8s;
typedef __attribute__((ext_vector_type(4))) short v4s;
typedef __attribute__((ext_vector_type(2))) unsigned v2u;
typedef __attribute__((ext_vector_type(4))) float v4f;

#define MFMA(a, b, c) __builtin_amdgcn_mfma_f32_16x16x32_bf16(a, b, c, 0, 0, 0)
#define QSCALE 0.18033688011112042f   // (1/8) * log2(e): attn softmax runs in exp2 space

__device__ __forceinline__ float bf2f(ushort_t u) {
    union { unsigned u; float f; } x; x.u = ((unsigned)u) << 16; return x.f;
}
__device__ __forceinline__ short f2bf(float f) {
    union { float f; unsigned u; } x; x.f = f;
    unsigned r = x.u + 0x7fffu + ((x.u >> 16) & 1u);   // RNE
    return (short)(r >> 16);
}

// ---------------- dtype detect: flag=1 if x is bf16-packed, 0 if fp32 ----------------
__global__ void detect_dtype(const unsigned* __restrict__ x, int* __restrict__ flag) {
    __shared__ int cnt;
    if (threadIdx.x == 0) cnt = 0;
    __syncthreads();
    unsigned w = x[threadIdx.x];
    int e = (w >> 7) & 0xFF;
    int hit = ((e >= 96 && e <= 135) || (w & 0xFFFFu) == 0) ? 1 : 0;
    atomicAdd(&cnt, hit);
    __syncthreads();
    if (threadIdx.x == 0) *flag = (cnt >= 160) ? 1 : 0;
}

// ---------------- convert x -> internal bf16 (8 elems/thread) ----------------
__global__ __launch_bounds__(256) void cvt_x(const void* __restrict__ xin,
                                             ushort_t* __restrict__ xb,
                                             const int* __restrict__ flagp, int n8) {
    int i = blockIdx.x * 256 + threadIdx.x;
    if (i >= n8) return;
    if (*flagp) {
        ((v8s*)xb)[i] = ((const v8s*)xin)[i];
    } else {
        const float* xf = (const float*)xin + (size_t)i * 8;
        v8s o;
        #pragma unroll
        for (int j = 0; j < 8; ++j) o[j] = f2bf(xf[j]);
        ((v8s*)xb)[i] = o;
    }
}

// ---------------- convert + transpose weights: out[c][r] = bf16(in[r][c]) ----------------
__global__ __launch_bounds__(256) void cvt_transpose(const void* __restrict__ in,
                                                     ushort_t* __restrict__ out,
                                                     const int* __restrict__ flagp,
                                                     int R, int C) {
    __shared__ ushort_t tile[32][33];
    int bx = blockIdx.x * 32, by = blockIdx.y * 32;
    int tx = threadIdx.x, ty = threadIdx.y;
    int isbf = *flagp;
    for (int i = ty; i < 32; i += 8) {
        size_t idx = (size_t)(by + i) * C + bx + tx;
        tile[i][tx] = isbf ? ((const ushort_t*)in)[idx]
                           : (ushort_t)f2bf(((const float*)in)[idx]);
    }
    __syncthreads();
    for (int i = ty; i < 32; i += 8) out[(size_t)(bx + i) * R + by + tx] = tile[tx][i];
}

// ---------------- RoPE table: tab[t][0:32]=cos(bf16-rounded), [32:64]=sin ----------------
__global__ __launch_bounds__(256) void rope_table(float* __restrict__ tab) {
    int idx = blockIdx.x * 256 + threadIdx.x;   // 65536 = 2048*32
    int t = idx >> 5, d = idx & 31;
    float inv_freq = __expf(-(float)d * 0.28782313662425575f);  // 10000^(-d/32)
    float ang = (float)t * inv_freq;
    float sn, cs;
    sincosf(ang, &sn, &cs);
    tab[t * 64 + d]      = bf2f((ushort_t)f2bf(cs));
    tab[t * 64 + 32 + d] = bf2f((ushort_t)f2bf(sn));
}

// ---------------- GEMM: C[M][N] = A[M][K] * BT[N][K]^T, bf16 in ----------------
// MODE 1: C store, fp32 if *flagp==0 else bf16 (out-proj).
// MODE 2: fused RoPE epilogue -> writes Qr (scaled), Kr, Vt (tiled); C unused.
template <int MODE>
__global__ __launch_bounds__(256) void gemm_bt(const ushort_t* __restrict__ A,
                                               const ushort_t* __restrict__ BT,
                                               void* __restrict__ C,
                                               const int* __restrict__ flagp,
                                               int M, int N, int K,
                                               ushort_t* __restrict__ Qp,
                                               ushort_t* __restrict__ Kp,
                                               ushort_t* __restrict__ Vp,
                                               const float* __restrict__ tab) {
    __shared__ __align__(16) ushort_t As[128 * 32];
    __shared__ __align__(16) ushort_t Bs[128 * 32];
    int tid = threadIdx.x;
    int lane = tid & 63;
    int lr = lane & 15, lc = lane >> 4;
    int w = tid >> 6;
    int wr = (w >> 1) * 64, wc = (w & 1) * 64;
    int m0 = blockIdx.y * 128, n0 = blockIdx.x * 128;

    int c0 = tid, c1 = tid + 256;
    int r0 = c0 >> 2, s0 = c0 & 3;
    int r1 = c1 >> 2, s1 = c1 & 3;

    v4f acc[4][4] = {};

    for (int kt = 0; kt < K; kt += 32) {
        v8s a0 = *(const v8s*)(A + (size_t)(m0 + r0) * K + kt + s0 * 8);
        v8s a1 = *(const v8s*)(A + (size_t)(m0 + r1) * K + kt + s1 * 8);
        v8s b0 = *(const v8s*)(BT + (size_t)(n0 + r0) * K + kt + s0 * 8);
        v8s b1 = *(const v8s*)(BT + (size_t)(n0 + r1) * K + kt + s1 * 8);
        __syncthreads();
        *(v8s*)(As + (size_t)c0 * 8) = a0;
        *(v8s*)(As + (size_t)c1 * 8) = a1;
        *(v8s*)(Bs + (size_t)c0 * 8) = b0;
        *(v8s*)(Bs + (size_t)c1 * 8) = b1;
        __syncthreads();

        v8s af[4], bfr[4];
        #pragma unroll
        for (int i = 0; i < 4; ++i)
            af[i] = *(const v8s*)(As + (wr + i * 16 + lr) * 32 + lc * 8);
        #pragma unroll
        for (int j = 0; j < 4; ++j)
            bfr[j] = *(const v8s*)(Bs + (wc + j * 16 + lr) * 32 + lc * 8);
        #pragma unroll
        for (int i = 0; i < 4; ++i)
            #pragma unroll
            for (int j = 0; j < 4; ++j)
                acc[i][j] = MFMA(af[i], bfr[j], acc[i][j]);
    }

    if (MODE == 1) {
        int store_f32 = (*flagp == 0);
        #pragma unroll
        for (int i = 0; i < 4; ++i)
            #pragma unroll
            for (int j = 0; j < 4; ++j)
                #pragma unroll
                for (int r = 0; r < 4; ++r) {
                    int row = m0 + wr + i * 16 + lc * 4 + r;
                    int col = n0 + wc + j * 16 + lr;
                    if (store_f32)
                        ((float*)C)[(size_t)row * N + col] = acc[i][j][r];
                    else
                        ((ushort_t*)C)[(size_t)row * N + col] = (ushort_t)f2bf(acc[i][j][r]);
                }
    } else {  // MODE 2: fused RoPE + reshape epilogue (N=3072 qkv GEMM)
        int region = n0 >> 10;                  // 0=Q 1=K 2=V
        int h = ((n0 & 1023) + wc) >> 6;
        if (region < 2) {
            const float sc = (region == 0) ? QSCALE : 1.0f;
            ushort_t* dst = (region == 0) ? Qp : Kp;
            #pragma unroll
            for (int i = 0; i < 4; ++i)
                #pragma unroll
                for (int j = 0; j < 2; ++j) {   // d = j*16+lr in [0,32); partner acc[i][j+2]
                    int d = j * 16 + lr;
                    #pragma unroll
                    for (int r = 0; r < 4; ++r) {
                        int tg = m0 + wr + i * 16 + lc * 4 + r;
                        int b = tg >> 11, tt = tg & 2047;
                        float cs = tab[tt * 64 + d], sn = tab[tt * 64 + 32 + d];
                        float x1 = acc[i][j][r], x2 = acc[i][j + 2][r];
                        size_t base = ((size_t)(b * 16 + h) * 2048 + tt) * 64 + d;
                        dst[base]      = (ushort_t)f2bf((x1 * cs - x2 * sn) * sc);
                        dst[base + 32] = (ushort_t)f2bf((x2 * cs + x1 * sn) * sc);
                    }
                }
        } else {  // V tiled: Vt[bh][s_tile][d*32 + s_in]
            #pragma unroll
            for (int i = 0; i < 4; ++i)
                #pragma unroll
                for (int j = 0; j < 4; ++j) {
                    int d = j * 16 + lr;
                    int tg0 = m0 + wr + i * 16 + lc * 4;
                    int b = tg0 >> 11, tt = tg0 & 2047;
                    v4s pk;
                    #pragma unroll
                    for (int r = 0; r < 4; ++r) pk[r] = f2bf(acc[i][j][r]);
                    size_t base = (size_t)(b * 16 + h) * 131072 + (size_t)(tt >> 5) * 2048
                                + (size_t)d * 32 + (tt & 31);
                    *(v4s*)(Vp + base) = pk;
                }
        }
    }
}

// ---------------- flash attention: 4 waves/block = 2 q-subtiles x 2 s-halves ----------------
// Each s-half group (2 waves) shares LDS-staged K/V tiles (double-buffered, 1 barrier/tile).
// 512 blocks -> 2 blocks/CU, 8 waves/CU (R9 had 1 wave/SIMD): TLP hides the per-tile chain.
// S^T = K*Q^T; no-max exp2 softmax; s-halves merged in LDS at the end (aliases staging).
__global__ __launch_bounds__(256) void attn(const ushort_t* __restrict__ Qr,
                                            const ushort_t* __restrict__ Kr,
                                            const ushort_t* __restrict__ Vt,
                                            ushort_t* __restrict__ AO) {
    __shared__ __align__(16) char lds[53248];
    // staging: group g: Ks @ g*16384 + p*4096, Vs @ g*16384 + 8192 + p*4096
    // P: wave W @ 32768 + W*5120 ([q64][s 32 pad 40] bf16)
    // merge (after loop, aliases staging+P[0]): MO[qsub] @ qsub*17408 (64x68 f32),
    //                                           Mli[qsub] @ 34816 + qsub*256
    int tid = threadIdx.x, lane = tid & 63, W = tid >> 6;
    int lr = lane & 15, lc = lane >> 4;
    int qsub = W & 1, sh = W >> 1;
    int L = blockIdx.x;                       // 512 blocks
    int bh = (L & 7) * 4 + ((L >> 3) & 3);    // XCD x owns bh 4x..4x+3 (if %8 maps)
    int qt = L >> 5;                          // 0..15
    int q0 = qt * 128 + qsub * 64;
    int b = bh >> 4, h = bh & 15;
    const ushort_t* Qb = Qr + ((size_t)bh * 2048 + q0) * 64;
    const ushort_t* Kb = Kr + (size_t)bh * 131072 + (size_t)sh * 65536;  // [s][64] row-major
    const ushort_t* Vb = Vt + (size_t)bh * 131072 + (size_t)sh * 65536;  // tiled [s_tile][2048]
    ushort_t* Pw  = (ushort_t*)(lds + 32768 + W * 5120);
    ushort_t* KsG = (ushort_t*)(lds + sh * 16384);          // + p*2048 shorts
    ushort_t* VsG = (ushort_t*)(lds + sh * 16384 + 8192);   // + p*2048 shorts

    // staging coords: group-local thread stages 2x16B of K and 2x16B of V per tile
    int gt = tid & 127;
    int c0 = gt, c1 = gt + 128;
    int kr0 = c0 >> 3, kc0 = c0 & 7, kr1 = c1 >> 3, kc1 = c1 & 7;
    const ushort_t* Kg0 = Kb + (size_t)kr0 * 64 + kc0 * 8;   // + tile*2048
    const ushort_t* Kg1 = Kb + (size_t)kr1 * 64 + kc1 * 8;
    int kl0 = kr0 * 64 + (kc0 ^ (kr0 & 7)) * 8;
    int kl1 = kr1 * 64 + (kc1 ^ (kr1 & 7)) * 8;
    const ushort_t* Vg0 = Vb + (size_t)c0 * 8;               // + tile*2048
    const ushort_t* Vg1 = Vb + (size_t)c1 * 8;
    int vl0 = c0 * 8, vl1 = c1 * 8;

    v8s qf[4][2];
    #pragma unroll
    for (int jq = 0; jq < 4; ++jq)
        #pragma unroll
        for (int kk = 0; kk < 2; ++kk)
            qf[jq][kk] = *(const v8s*)(Qb + (size_t)(jq * 16 + lr) * 64 + kk * 32 + lc * 8);

    v4f o[4][4] = {};
    float li[4] = {0.f, 0.f, 0.f, 0.f};

    // preload tile 0 into buf0; prefetch tile 1 into regs
    v8s ka = *(const v8s*)(Kg0), kb2 = *(const v8s*)(Kg1);
    v8s va = *(const v8s*)(Vg0), vb2 = *(const v8s*)(Vg1);
    *(v8s*)(KsG + kl0) = ka;
    *(v8s*)(KsG + kl1) = kb2;
    *(v8s*)(VsG + vl0) = va;
    *(v8s*)(VsG + vl1) = vb2;
    ka  = *(const v8s*)(Kg0 + 2048);
    kb2 = *(const v8s*)(Kg1 + 2048);
    va  = *(const v8s*)(Vg0 + 2048);
    vb2 = *(const v8s*)(Vg1 + 2048);
    __syncthreads();

    #pragma unroll 1
    for (int t = 0; t < 32; ++t) {
        int p = t & 1;
        const ushort_t* Kl = KsG + p * 2048;
        const ushort_t* Vl = VsG + p * 2048;

        v8s kf[2][2], vf[4];
        #pragma unroll
        for (int hh = 0; hh < 2; ++hh)
            #pragma unroll
            for (int kk = 0; kk < 2; ++kk)
                kf[hh][kk] = *(const v8s*)(Kl + (hh * 16 + lr) * 64 + (((kk * 4 + lc) ^ (lr & 7)) * 8));
        #pragma unroll
        for (int i = 0; i < 4; ++i)
            vf[i] = *(const v8s*)(Vl + (i * 16 + lr) * 32 + lc * 8);

        v4f St[2][4] = {};
        #pragma unroll
        for (int hh = 0; hh < 2; ++hh)
            #pragma unroll
            for (int jq = 0; jq < 4; ++jq) {
                St[hh][jq] = MFMA(kf[hh][0], qf[jq][0], St[hh][jq]);
                St[hh][jq] = MFMA(kf[hh][1], qf[jq][1], St[hh][jq]);
            }

        // stage tile t+1 (regs were loaded last iteration); prefetch t+2
        if (t + 1 < 32) {
            ushort_t* Kn = KsG + (p ^ 1) * 2048;
            ushort_t* Vn = VsG + (p ^ 1) * 2048;
            *(v8s*)(Kn + kl0) = ka;
            *(v8s*)(Kn + kl1) = kb2;
            *(v8s*)(Vn + vl0) = va;
            *(v8s*)(Vn + vl1) = vb2;
        }
        if (t + 2 < 32) {
            ka  = *(const v8s*)(Kg0 + (size_t)(t + 2) * 2048);
            kb2 = *(const v8s*)(Kg1 + (size_t)(t + 2) * 2048);
            va  = *(const v8s*)(Vg0 + (size_t)(t + 2) * 2048);
            vb2 = *(const v8s*)(Vg1 + (size_t)(t + 2) * 2048);
        }

        // softmax (exp2 space) + pack P
        #pragma unroll
        for (int jq = 0; jq < 4; ++jq)
            #pragma unroll
            for (int hh = 0; hh < 2; ++hh) {
                #pragma unroll
                for (int r = 0; r < 4; ++r) {
                    float ev = __builtin_amdgcn_exp2f(St[hh][jq][r]);
                    St[hh][jq][r] = ev;
                    li[jq] += ev;
                }
                unsigned d0 = __builtin_amdgcn_perm(__float_as_uint(St[hh][jq][1]),
                                                    __float_as_uint(St[hh][jq][0]), 0x07060302u);
                unsigned d1 = __builtin_amdgcn_perm(__float_as_uint(St[hh][jq][3]),
                                                    __float_as_uint(St[hh][jq][2]), 0x07060302u);
                v2u pk = {d0, d1};
                *(v2u*)(Pw + (jq * 16 + lr) * 40 + hh * 16 + lc * 4) = pk;
            }
        __builtin_amdgcn_s_waitcnt(0xc07f);   // lgkmcnt(0): own P writes visible
        #pragma unroll
        for (int jq = 0; jq < 4; ++jq) {
            v8s pf = *(const v8s*)(Pw + (jq * 16 + lr) * 40 + lc * 8);
            #pragma unroll
            for (int i = 0; i < 4; ++i)
                o[i][jq] = MFMA(vf[i], pf, o[i][jq]);
        }
        __syncthreads();   // staging of t+1 visible; all waves done with buf p
    }

    // li wave-reduce, then merge s-halves per q-subtile
    #pragma unroll
    for (int jq = 0; jq < 4; ++jq) {
        li[jq] += __shfl_xor(li[jq], 16);
        li[jq] += __shfl_xor(li[jq], 32);
    }
    float* MO = (float*)(lds + qsub * 17408);
    float* Ml = (float*)(lds + 34816 + qsub * 256);
    __syncthreads();   // everyone done with staging/P regions
    if (sh == 1) {
        #pragma unroll
        for (int jq = 0; jq < 4; ++jq) {
            #pragma unroll
            for (int i = 0; i < 4; ++i)
                *(v4f*)(MO + (jq * 16 + lr) * 68 + i * 16 + lc * 4) = o[i][jq];
            if (lc == 0) Ml[jq * 16 + lr] = li[jq];
        }
    }
    __syncthreads();
    if (sh == 0) {
        #pragma unroll
        for (int jq = 0; jq < 4; ++jq) {
            float inv = 1.0f / (li[jq] + Ml[jq * 16 + lr]);
            int t = q0 + jq * 16 + lr;
            #pragma unroll
            for (int i = 0; i < 4; ++i) {
                v4f m = *(const v4f*)(MO + (jq * 16 + lr) * 68 + i * 16 + lc * 4);
                v4s pk;
                #pragma unroll
                for (int r = 0; r < 4; ++r) pk[r] = f2bf((o[i][jq][r] + m[r]) * inv);
                *(v4s*)(AO + (size_t)(b * 2048 + t) * 1024 + h * 64 + i * 16 + lc * 4) = pk;
            }
        }
    }
}

extern "C" void kernel_launch(void* const* d_in, const int* in_sizes, int n_in,
                              void* d_out, int out_size, void* d_ws, size_t ws_size,
                              hipStream_t stream) {
    char* ws = (char*)d_ws;
    int*      flag  = (int*)ws;                      // 256 B
    ushort_t* wqkvT = (ushort_t*)(ws + 256);         // 6 MB
    ushort_t* woT   = (ushort_t*)(ws + 6291712);     // 2 MB
    ushort_t* xb    = (ushort_t*)(ws + 8388864);     // 8 MB
    ushort_t* Qr    = (ushort_t*)(ws + 16777472);    // 8 MB
    ushort_t* Kr    = (ushort_t*)(ws + 25166080);    // 8 MB
    ushort_t* Vt    = (ushort_t*)(ws + 33554688);    // 8 MB
    ushort_t* AO    = (ushort_t*)(ws + 41943296);    // 8 MB
    float*    tab   = (float*)(ws + 50331904);       // 512 KB

    detect_dtype<<<1, 256, 0, stream>>>((const unsigned*)d_in[0], flag);
    rope_table<<<256, 256, 0, stream>>>(tab);
    cvt_x<<<2048, 256, 0, stream>>>(d_in[0], xb, flag, 524288);
    dim3 tb(32, 8);
    cvt_transpose<<<dim3(96, 32), tb, 0, stream>>>(d_in[1], wqkvT, flag, 1024, 3072);
    cvt_transpose<<<dim3(32, 32), tb, 0, stream>>>(d_in[2], woT, flag, 1024, 1024);
    gemm_bt<2><<<dim3(24, 32), 256, 0, stream>>>(xb, wqkvT, nullptr, flag, 4096, 3072, 1024,
                                                 Qr, Kr, Vt, tab);
    attn<<<512, 256, 0, stream>>>(Qr, Kr, Vt, AO);
    gemm_bt<1><<<dim3(8, 32), 256, 0, stream>>>(AO, woT, d_out, flag, 4096, 1024, 1024,
                                                nullptr, nullptr, nullptr, nullptr);
}